// Round 15
// baseline (423.004 us; speedup 1.0000x reference)
//
#include <hip/hip_runtime.h>

#define EDIM 64
#define RCAP 6144    // per-bucket region capacity (mean ~5115, +14 sigma)
#define NBMAX 512
#define P1_BLOCKS 1024

typedef __attribute__((ext_vector_type(8))) short short8;
typedef __attribute__((ext_vector_type(4))) float f32x4;

// f32 -> bf16 round-to-nearest-even
__device__ __forceinline__ unsigned int f2bf(float x) {
  unsigned int u = __float_as_uint(x);
  u += 0x7FFFu + ((u >> 16) & 1u);
  return u >> 16;
}
__device__ __forceinline__ float bflo(unsigned int u) {
  return __uint_as_float(u << 16);
}
__device__ __forceinline__ float bfhi(unsigned int u) {
  return __uint_as_float(u & 0xFFFF0000u);
}
__device__ __forceinline__ float bf2f(unsigned short s) {
  return __uint_as_float(((unsigned int)s) << 16);
}

// ---------------------------------------------------------------------------
// Fused prep: blocks [0, P1_BLOCKS) run bucket pass 1 (latency/LDS-atomic
// bound); remaining blocks run the f32->bf16 table conversion (BW bound).
// ---------------------------------------------------------------------------
__global__ __launch_bounds__(256) void prep_kernel(
    // pass1 (CSR/CSC bucket scatter)
    const int* __restrict__ rows, const int* __restrict__ cols,
    const float* __restrict__ up_vals, const float* __restrict__ pu_vals,
    int* __restrict__ curU, int* __restrict__ curP,
    int2* __restrict__ regU, int2* __restrict__ regP,
    int nnz, int shU, int shP, int nbU, int nbP,
    // tobf16 (3 tables)
    const float4* __restrict__ s0, const float4* __restrict__ s1,
    const float4* __restrict__ s2, uint2* __restrict__ d0,
    uint2* __restrict__ d1, uint2* __restrict__ d2, int n4) {
  __shared__ int cntU[NBMAX], cntP[NBMAX];
  __shared__ int cuU[NBMAX], cuP[NBMAX];
  const int tid = threadIdx.x;

  if (blockIdx.x < P1_BLOCKS) {
    // ---- bucket pass 1 ----
    for (int i = tid; i < nbU; i += 256) cntU[i] = 0;
    for (int i = tid; i < nbP; i += 256) cntP[i] = 0;
    __syncthreads();
    const int chunk = (nnz + P1_BLOCKS - 1) / P1_BLOCKS;
    const int s = blockIdx.x * chunk;
    const int e = min(nnz, s + chunk);
    for (int i = s + tid; i < e; i += 256) {
      atomicAdd(&cntU[rows[i] >> shU], 1);
      atomicAdd(&cntP[cols[i] >> shP], 1);
    }
    __syncthreads();
    for (int i = tid; i < nbU; i += 256) {
      const int c = cntU[i];
      cuU[i] = c ? atomicAdd(&curU[i], c) : 0;
    }
    for (int i = tid; i < nbP; i += 256) {
      const int c = cntP[i];
      cuP[i] = c ? atomicAdd(&curP[i], c) : 0;
    }
    __syncthreads();
    const int maskU = (1 << shU) - 1, maskP = (1 << shP) - 1;
    for (int i = s + tid; i < e; i += 256) {
      const int r = rows[i], c = cols[i];
      const int bu = r >> shU, bp = c >> shP;
      const int pu = atomicAdd(&cuU[bu], 1);
      if (pu < RCAP)
        regU[bu * RCAP + pu] =
            make_int2(c | ((r & maskU) << 18), __float_as_int(up_vals[i]));
      const int pp = atomicAdd(&cuP[bp], 1);
      if (pp < RCAP)
        regP[bp * RCAP + pp] =
            make_int2(r | ((c & maskP) << 18), __float_as_int(pu_vals[i]));
    }
  } else {
    // ---- f32 -> bf16 tables ----
    const int bid = blockIdx.x - P1_BLOCKS;
    const int stride = (gridDim.x - P1_BLOCKS) * 256;
    for (int i = bid * 256 + tid; i < 3 * n4; i += stride) {
      const int t = i / n4, j = i - t * n4;
      const float4* sp = (t == 0) ? s0 : ((t == 1) ? s1 : s2);
      uint2* dp = (t == 0) ? d0 : ((t == 1) ? d1 : d2);
      const float4 v = sp[j];
      uint2 o;
      o.x = f2bf(v.x) | (f2bf(v.y) << 16);
      o.y = f2bf(v.z) | (f2bf(v.w) << 16);
      dp[j] = o;
    }
  }
}

// ---------------------------------------------------------------------------
// Merged parallel exclusive scan of both bucket-total arrays (one block).
// ---------------------------------------------------------------------------
__device__ __forceinline__ void scan_one(const int* __restrict__ cnt,
                                         int* __restrict__ base, int nb,
                                         int* wsum) {
  const int tid = threadIdx.x;
  const int lane = tid & 63, wid = tid >> 6;
  const int v = (tid < nb) ? cnt[tid] : 0;
  int sc = v;
  for (int d = 1; d < 64; d <<= 1) {
    const int o = __shfl_up(sc, d);
    if (lane >= d) sc += o;
  }
  if (lane == 63) wsum[wid] = sc;
  __syncthreads();
  int woff = 0;
  for (int w = 0; w < wid; ++w) woff += wsum[w];
  if (tid < nb) base[tid] = woff + sc - v;
  __syncthreads();
}

__global__ __launch_bounds__(512) void bucket_scan2_kernel(
    const int* __restrict__ curU, int* __restrict__ baseU, int nbU,
    const int* __restrict__ curP, int* __restrict__ baseP, int nbP) {
  __shared__ int wsum[8];
  scan_one(curU, baseU, nbU, wsum);
  scan_one(curP, baseP, nbP, wsum);
}

// ---------------------------------------------------------------------------
// Merged bucket pass 2 (both sides): per-bucket LDS key histogram + scan ->
// compact ptr[] and final CSR payload scatter.
// ---------------------------------------------------------------------------
__global__ __launch_bounds__(256) void bucket_pass2_kernel(
    const int* __restrict__ curU, const int* __restrict__ baseU,
    const int2* __restrict__ regU, int* __restrict__ ptrU,
    int2* __restrict__ csrU, int nkeyU, int shU,
    const int* __restrict__ curP, const int* __restrict__ baseP,
    const int2* __restrict__ regP, int* __restrict__ ptrP,
    int2* __restrict__ csrP, int nkeyP, int shP, int nbU) {
  __shared__ int hist[NBMAX];
  const int tid = threadIdx.x;
  int b = blockIdx.x;
  const int* gCur;
  const int* gBase;
  const int2* reg;
  int* ptr;
  int2* csr;
  int nkey, sh;
  if (b < nbU) {
    gCur = curU; gBase = baseU; reg = regU; ptr = ptrU; csr = csrU;
    nkey = nkeyU; sh = shU;
  } else {
    b -= nbU;
    gCur = curP; gBase = baseP; reg = regP; ptr = ptrP; csr = csrP;
    nkey = nkeyP; sh = shP;
  }
  const int kpb = 1 << sh;
  const int n = min(gCur[b], RCAP);
  const int rb = b * RCAP;
  const int cb = gBase[b];
  const int keyLo = b << sh;
  for (int i = tid; i < kpb; i += 256) hist[i] = 0;
  __syncthreads();
  for (int i = tid; i < n; i += 256)
    atomicAdd(&hist[(unsigned)reg[rb + i].x >> 18], 1);
  __syncthreads();
  if (tid == 0) {
    int run = 0;
    for (int k = 0; k < kpb; ++k) {
      const int c = hist[k];
      hist[k] = run;
      run += c;
    }
  }
  __syncthreads();
  for (int k = tid; k < kpb; k += 256) {
    const int key = keyLo + k;
    if (key < nkey) ptr[key] = cb + hist[k];
  }
  __syncthreads();
  for (int i = tid; i < n; i += 256) {
    const int2 ent = reg[rb + i];
    const int k = (unsigned)ent.x >> 18;
    const int pos = atomicAdd(&hist[k], 1);
    csr[cb + pos] = make_int2(ent.x & 0x3FFFF, ent.y);
  }
}

// ---------------------------------------------------------------------------
// Per-user gather over bf16 tables -> bf16 g/s/p outputs [U][64].
// 16 lanes x 8B per row, 4 nnz per step (round-10 proven structure).
// ---------------------------------------------------------------------------
__global__ __launch_bounds__(256) void user_gather_kernel(
    const int* __restrict__ ptrU, const int2* __restrict__ csrU,
    const unsigned short* __restrict__ tblG,
    const unsigned short* __restrict__ tblS,
    const unsigned short* __restrict__ tblC,
    unsigned short* __restrict__ gw, unsigned short* __restrict__ sw,
    unsigned short* __restrict__ pw, int U, int nnz) {
  const int lane = threadIdx.x & 63;
  const int sub = lane >> 4, d4 = lane & 15;
  const int wv = blockIdx.x * 4 + (threadIdx.x >> 6);
  const int nW = gridDim.x * 4;
  for (int u = wv; u < U; u += nW) {
    const int start = ptrU[u];
    const int end = (u + 1 < U) ? ptrU[u + 1] : nnz;
    float4 g4 = {0, 0, 0, 0}, s4 = {0, 0, 0, 0}, p4 = {0, 0, 0, 0};
    for (int k0 = start; k0 < end; k0 += 64) {
      int c_v = 0;
      float v_v = 0.f;
      const int kk = k0 + lane;
      if (kk < end) {
        const int2 e = csrU[kk];
        c_v = e.x;
        v_v = __int_as_float(e.y);
      }
      const int steps = (min(64, end - k0) + 3) >> 2;
      for (int t = 0; t < steps; ++t) {
        const int src = t * 4 + sub;
        const int cc = __shfl(c_v, src);
        const float vv = __shfl(v_v, src);
        const size_t rb = (size_t)cc * EDIM;
        const uint2 gg = ((const uint2*)(tblG + rb))[d4];
        const uint2 ss = ((const uint2*)(tblS + rb))[d4];
        const uint2 pp = ((const uint2*)(tblC + rb))[d4];
        g4.x += vv * bflo(gg.x); g4.y += vv * bfhi(gg.x);
        g4.z += vv * bflo(gg.y); g4.w += vv * bfhi(gg.y);
        s4.x += vv * bflo(ss.x); s4.y += vv * bfhi(ss.x);
        s4.z += vv * bflo(ss.y); s4.w += vv * bfhi(ss.y);
        p4.x += vv * bflo(pp.x); p4.y += vv * bfhi(pp.x);
        p4.z += vv * bflo(pp.y); p4.w += vv * bfhi(pp.y);
      }
    }
#pragma unroll
    for (int m = 16; m <= 32; m <<= 1) {
      g4.x += __shfl_xor(g4.x, m); g4.y += __shfl_xor(g4.y, m);
      g4.z += __shfl_xor(g4.z, m); g4.w += __shfl_xor(g4.w, m);
      s4.x += __shfl_xor(s4.x, m); s4.y += __shfl_xor(s4.y, m);
      s4.z += __shfl_xor(s4.z, m); s4.w += __shfl_xor(s4.w, m);
      p4.x += __shfl_xor(p4.x, m); p4.y += __shfl_xor(p4.y, m);
      p4.z += __shfl_xor(p4.z, m); p4.w += __shfl_xor(p4.w, m);
    }
    if (sub == 0) {
      uint2 gp2, sp2, pp2;
      gp2.x = f2bf(g4.x) | (f2bf(g4.y) << 16);
      gp2.y = f2bf(g4.z) | (f2bf(g4.w) << 16);
      sp2.x = f2bf(s4.x) | (f2bf(s4.y) << 16);
      sp2.y = f2bf(s4.z) | (f2bf(s4.w) << 16);
      pp2.x = f2bf(p4.x) | (f2bf(p4.y) << 16);
      pp2.y = f2bf(p4.z) | (f2bf(p4.w) << 16);
      ((uint2*)(gw + (size_t)u * EDIM))[d4] = gp2;
      ((uint2*)(sw + (size_t)u * EDIM))[d4] = sp2;
      ((uint2*)(pw + (size_t)u * EDIM))[d4] = pp2;
    }
  }
}

// ---------------------------------------------------------------------------
// Fusion as bf16 MFMA GEMM: msg[U,448] @ W^T[448,64] + bias + gated merge.
// ---------------------------------------------------------------------------
#define FM_BLK 256
__global__ __launch_bounds__(FM_BLK) void fusion_mfma_kernel(
    const unsigned short* __restrict__ gbf, const unsigned short* __restrict__ sbf,
    const unsigned short* __restrict__ pbf, const float* __restrict__ uemb,
    const float* __restrict__ W, const float* __restrict__ b,
    unsigned short* __restrict__ hbf, int U) {
  __shared__ unsigned short wlds[7 * 2 * 4 * 64 * 8];  // 57344 B
  for (int fe = threadIdx.x; fe < 7 * 2 * 4 * 64; fe += FM_BLK) {
    const int ln = fe & 63;
    const int n = (fe >> 6) & 3;
    const int h = (fe >> 8) & 1;
    const int blk = fe >> 9;
    const int e = n * 16 + (ln & 15);
    const int f0 = blk * 64 + h * 32 + (ln >> 4) * 8;
    const float* wsrc = W + (size_t)e * 448 + f0;
    uint4 w4;
    w4.x = f2bf(wsrc[0]) | (f2bf(wsrc[1]) << 16);
    w4.y = f2bf(wsrc[2]) | (f2bf(wsrc[3]) << 16);
    w4.z = f2bf(wsrc[4]) | (f2bf(wsrc[5]) << 16);
    w4.w = f2bf(wsrc[6]) | (f2bf(wsrc[7]) << 16);
    ((uint4*)wlds)[fe] = w4;
  }
  __syncthreads();

  const int l = threadIdx.x & 63;
  const int row16 = l & 15, kg = l >> 4;
  const int wv = blockIdx.x * (FM_BLK / 64) + (threadIdx.x >> 6);
  const int nWv = gridDim.x * (FM_BLK / 64);
  float bias4[4];
#pragma unroll
  for (int n = 0; n < 4; ++n) bias4[n] = b[n * 16 + row16];

  const int nT = (U + 15) >> 4;
  for (int t = wv; t < nT; t += nWv) {
    const int u0 = t * 16;
    f32x4 acc0 = {0, 0, 0, 0}, acc1 = {0, 0, 0, 0};
    f32x4 acc2 = {0, 0, 0, 0}, acc3 = {0, 0, 0, 0};
    const int ua = min(u0 + row16, U - 1);  // clamped A-row user
#pragma unroll
    for (int h = 0; h < 2; ++h) {
      const size_t off = (size_t)ua * EDIM + h * 32 + kg * 8;
      short8 gfr = *(const short8*)(gbf + off);
      short8 sfr = *(const short8*)(sbf + off);
      short8 pfr = *(const short8*)(pbf + off);
      float gf[8], sf[8], pf[8];
#pragma unroll
      for (int j = 0; j < 8; ++j) {
        gf[j] = bf2f((unsigned short)gfr[j]);
        sf[j] = bf2f((unsigned short)sfr[j]);
        pf[j] = bf2f((unsigned short)pfr[j]);
      }
      short8 gs, gp, sp, gsp;
#pragma unroll
      for (int j = 0; j < 8; ++j) {
        const float a = gf[j] * sf[j];
        gs[j] = (short)f2bf(a);
        gp[j] = (short)f2bf(gf[j] * pf[j]);
        sp[j] = (short)f2bf(sf[j] * pf[j]);
        gsp[j] = (short)f2bf(a * pf[j]);
      }
      short8 afr[7] = {gfr, sfr, pfr, gs, gp, sp, gsp};
#pragma unroll
      for (int blk = 0; blk < 7; ++blk) {
        const int fb = blk * 512 + h * 256;
        const short8 b0 = *(const short8*)(wlds + (size_t)(fb + 0 * 64 + l) * 8);
        const short8 b1 = *(const short8*)(wlds + (size_t)(fb + 1 * 64 + l) * 8);
        const short8 b2 = *(const short8*)(wlds + (size_t)(fb + 2 * 64 + l) * 8);
        const short8 b3 = *(const short8*)(wlds + (size_t)(fb + 3 * 64 + l) * 8);
        acc0 = __builtin_amdgcn_mfma_f32_16x16x32_bf16(afr[blk], b0, acc0, 0, 0, 0);
        acc1 = __builtin_amdgcn_mfma_f32_16x16x32_bf16(afr[blk], b1, acc1, 0, 0, 0);
        acc2 = __builtin_amdgcn_mfma_f32_16x16x32_bf16(afr[blk], b2, acc2, 0, 0, 0);
        acc3 = __builtin_amdgcn_mfma_f32_16x16x32_bf16(afr[blk], b3, acc3, 0, 0, 0);
      }
    }
#pragma unroll
    for (int r = 0; r < 4; ++r) {
      const int u = u0 + kg * 4 + r;
      if (u < U) {
        const size_t ubase = (size_t)u * EDIM + row16;
        {
          const float me = acc0[r] + bias4[0];
          const float ue = uemb[ubase + 0];
          hbf[ubase + 0] = (unsigned short)f2bf(me + ue + me * ue);
        }
        {
          const float me = acc1[r] + bias4[1];
          const float ue = uemb[ubase + 16];
          hbf[ubase + 16] = (unsigned short)f2bf(me + ue + me * ue);
        }
        {
          const float me = acc2[r] + bias4[2];
          const float ue = uemb[ubase + 32];
          hbf[ubase + 32] = (unsigned short)f2bf(me + ue + me * ue);
        }
        {
          const float me = acc3[r] + bias4[3];
          const float ue = uemb[ubase + 48];
          hbf[ubase + 48] = (unsigned short)f2bf(me + ue + me * ue);
        }
      }
    }
  }
}

// ---------------------------------------------------------------------------
// Per-POI gather over bf16 hg with 4-deep load pipeline (padded entries have
// v=0 from the batch-load guard, so extra issued gathers contribute exactly
// 0). csrP = {row, pu_val}; fused mean: out = init + (L/2)*acc.
// ---------------------------------------------------------------------------
__global__ __launch_bounds__(256) void poi_gather_kernel(
    const int* __restrict__ ptrP, const int2* __restrict__ csrP,
    const unsigned short* __restrict__ hbf, const float* __restrict__ init,
    const int* __restrict__ num_layers, float* __restrict__ out, int P,
    int nnz) {
  const float scale = 0.5f * (float)num_layers[0];
  const int lane = threadIdx.x & 63;
  const int sub = lane >> 4, d4 = lane & 15;
  const int wv = blockIdx.x * 4 + (threadIdx.x >> 6);
  const int nW = gridDim.x * 4;
  for (int c = wv; c < P; c += nW) {
    const int start = ptrP[c];
    const int end = (c + 1 < P) ? ptrP[c + 1] : nnz;
    float4 a4 = {0, 0, 0, 0};
    for (int k0 = start; k0 < end; k0 += 64) {
      int r_v = 0;
      float v_v = 0.f;
      const int kk = k0 + lane;
      if (kk < end) {
        const int2 e = csrP[kk];
        r_v = e.x;
        v_v = __int_as_float(e.y);
      }
      const int steps = (min(64, end - k0) + 3) >> 2;
      for (int t0 = 0; t0 < steps; t0 += 4) {
        uint2 h[4];
        float vq[4];
#pragma unroll
        for (int q = 0; q < 4; ++q) {
          const int src = ((t0 + q) * 4 + sub) & 63;
          const int rr = __shfl(r_v, src);
          vq[q] = __shfl(v_v, src);
          h[q] = ((const uint2*)(hbf + (size_t)rr * EDIM))[d4];
        }
#pragma unroll
        for (int q = 0; q < 4; ++q) {
          a4.x += vq[q] * bflo(h[q].x);
          a4.y += vq[q] * bfhi(h[q].x);
          a4.z += vq[q] * bflo(h[q].y);
          a4.w += vq[q] * bfhi(h[q].y);
        }
      }
    }
#pragma unroll
    for (int m = 16; m <= 32; m <<= 1) {
      a4.x += __shfl_xor(a4.x, m); a4.y += __shfl_xor(a4.y, m);
      a4.z += __shfl_xor(a4.z, m); a4.w += __shfl_xor(a4.w, m);
    }
    if (sub == 0) {
      const float4 iv = ((const float4*)(init + (size_t)c * EDIM))[d4];
      float4 o;
      o.x = iv.x + scale * a4.x;
      o.y = iv.y + scale * a4.y;
      o.z = iv.z + scale * a4.z;
      o.w = iv.w + scale * a4.w;
      ((float4*)(out + (size_t)c * EDIM))[d4] = o;
    }
  }
}

extern "C" void kernel_launch(void* const* d_in, const int* in_sizes, int n_in,
                              void* d_out, int out_size, void* d_ws,
                              size_t ws_size, hipStream_t stream) {
  const float* init = (const float*)d_in[0];
  const float* colp = (const float*)d_in[1];
  const float* geo = (const float*)d_in[2];
  const float* seq = (const float*)d_in[3];
  const float* uemb = (const float*)d_in[4];
  const int* up_rows = (const int*)d_in[5];
  const int* up_cols = (const int*)d_in[6];
  const float* up_vals = (const float*)d_in[7];
  const float* pu_vals = (const float*)d_in[8];
  const float* W = (const float*)d_in[9];
  const float* b = (const float*)d_in[10];
  const int* num_layers = (const int*)d_in[11];

  const int U = in_sizes[4] / EDIM;   // 100000 users
  const int P = in_sizes[0] / EDIM;   // 200000 POIs
  const int NNZ = in_sizes[5];

  const int SHU = 8, SHP = 9;                 // 256 users / 512 POIs per bucket
  const int NBU = (U + 255) >> 8;             // 391
  const int NBP = (P + 511) >> 9;             // 391

  // ---- workspace layout (~97 MB) ----
  int* ptrU = (int*)d_ws;                     // U (0.4 MB)
  int* ptrP = ptrU + U;                       // P (0.8 MB)
  int* curU = ptrP + P;                       // 512
  int* curP = curU + NBMAX;                   // 512
  int* baseU = curP + NBMAX;                  // 512
  int* baseP = baseU + NBMAX;                 // 512
  int2* csrP = (int2*)(baseP + NBMAX);        // NNZ {row, pu_val} (16 MB)
  int2* csrU = csrP + NNZ;                    // NNZ {col, up_val} (16 MB)
  unsigned short* tblS = (unsigned short*)(csrU + NNZ);  // P*64 bf16 (25.6 MB)
  unsigned short* gbf = tblS + (size_t)P * EDIM;         // U*64 bf16 (12.8 MB)
  unsigned short* sbf = gbf + (size_t)U * EDIM;          // 12.8 MB
  unsigned short* pbf = sbf + (size_t)U * EDIM;          // 12.8 MB
  // hbf (12.8 MB) overlays csrU (16 MB, dead after user_gather)
  unsigned short* hbf = (unsigned short*)csrU;
  // bucket regions (2 x 391*6144 int2 = 38.4 MB) overlay gbf..pbf (38.4 MB,
  // dead until user_gather writes them after pass2 is done)
  int2* regU = (int2*)gbf;
  int2* regP = regU + (size_t)NBU * RCAP;
  // d_out scratch: two bf16 tables (dead before final out write)
  unsigned short* tblG = (unsigned short*)d_out;          // P*64
  unsigned short* tblC = tblG + (size_t)P * EDIM;         // P*64
  float* out = (float*)d_out;

  hipMemsetAsync(curU, 0, 2 * NBMAX * sizeof(int), stream);

  prep_kernel<<<P1_BLOCKS + 2048, 256, 0, stream>>>(
      up_rows, up_cols, up_vals, pu_vals, curU, curP, regU, regP, NNZ, SHU,
      SHP, NBU, NBP, (const float4*)geo, (const float4*)seq,
      (const float4*)colp, (uint2*)tblG, (uint2*)tblS, (uint2*)tblC,
      P * (EDIM / 4));

  bucket_scan2_kernel<<<1, 512, 0, stream>>>(curU, baseU, NBU, curP, baseP,
                                             NBP);

  bucket_pass2_kernel<<<NBU + NBP, 256, 0, stream>>>(
      curU, baseU, regU, ptrU, csrU, U, SHU, curP, baseP, regP, ptrP, csrP, P,
      SHP, NBU);

  user_gather_kernel<<<2048, 256, 0, stream>>>(ptrU, csrU, tblG, tblS, tblC,
                                               gbf, sbf, pbf, U, NNZ);

  fusion_mfma_kernel<<<512, FM_BLK, 0, stream>>>(gbf, sbf, pbf, uemb, W, b,
                                                 hbf, U);

  poi_gather_kernel<<<2048, 256, 0, stream>>>(ptrP, csrP, hbf, init,
                                              num_layers, out, P, NNZ);
}

// Round 16
// 400.090 us; speedup vs baseline: 1.0573x; 1.0573x over previous
//
#include <hip/hip_runtime.h>

#define EDIM 64
#define RCAP 6144    // per-bucket region capacity (mean ~5115, +14 sigma)
#define NBMAX 512
#define P1_BLOCKS 1024
#define CHUNK 2048   // >= ceil(NNZ / P1_BLOCKS)

typedef __attribute__((ext_vector_type(8))) short short8;
typedef __attribute__((ext_vector_type(4))) float f32x4;

// f32 -> bf16 round-to-nearest-even
__device__ __forceinline__ unsigned int f2bf(float x) {
  unsigned int u = __float_as_uint(x);
  u += 0x7FFFu + ((u >> 16) & 1u);
  return u >> 16;
}
__device__ __forceinline__ float bflo(unsigned int u) {
  return __uint_as_float(u << 16);
}
__device__ __forceinline__ float bfhi(unsigned int u) {
  return __uint_as_float(u & 0xFFFF0000u);
}
__device__ __forceinline__ float bf2f(unsigned short s) {
  return __uint_as_float(((unsigned int)s) << 16);
}

// ---------------------------------------------------------------------------
// One side of sorted pass1: LDS histogram -> LDS scan -> global range
// reserve -> LDS counting-sort scatter -> run-coalesced global writeout.
// ---------------------------------------------------------------------------
__device__ __forceinline__ void p1_side(
    const int* __restrict__ keys, const int* __restrict__ pay,
    const float* __restrict__ vals, int s, int n, int sh, int nb,
    int* __restrict__ curG, int2* __restrict__ reg, int2* stg,
    unsigned short* sbkt, int* cnt, int* cur, int* gbase, int tid) {
  for (int i = tid; i < nb; i += 256) cnt[i] = 0;
  __syncthreads();
  for (int i = tid; i < n; i += 256) atomicAdd(&cnt[keys[s + i] >> sh], 1);
  __syncthreads();
  if (tid == 0) {
    int run = 0;
    for (int b = 0; b < nb; ++b) {
      cur[b] = run;
      run += cnt[b];
    }
  }
  __syncthreads();
  for (int b = tid; b < nb; b += 256) {
    const int c = cnt[b];
    gbase[b] = c ? atomicAdd(&curG[b], c) : 0;
  }
  __syncthreads();
  const int mask = (1 << sh) - 1;
  for (int i = tid; i < n; i += 256) {
    const int k = keys[s + i];
    const int b = k >> sh;
    const int pos = atomicAdd(&cur[b], 1);
    stg[pos] = make_int2(pay[s + i] | ((k & mask) << 18),
                         __float_as_int(vals[s + i]));
    sbkt[pos] = (unsigned short)b;
  }
  __syncthreads();
  // cur[b] == ldsBase[b] + cnt[b]; cnt intact -> ldsBase = cur - cnt.
  for (int j = tid; j < n; j += 256) {
    const int b = sbkt[j];
    const int off = gbase[b] + (j - (cur[b] - cnt[b]));
    if (off < RCAP) reg[b * RCAP + off] = stg[j];
  }
  __syncthreads();
}

// ---------------------------------------------------------------------------
// Fused prep: blocks [0, P1_BLOCKS) run SORTED bucket pass 1 (run-coalesced
// region writes); remaining blocks run the f32->bf16 table conversion.
// ---------------------------------------------------------------------------
__global__ __launch_bounds__(256) void prep_kernel(
    const int* __restrict__ rows, const int* __restrict__ cols,
    const float* __restrict__ up_vals, const float* __restrict__ pu_vals,
    int* __restrict__ curU, int* __restrict__ curP,
    int2* __restrict__ regU, int2* __restrict__ regP,
    int nnz, int shU, int shP, int nbU, int nbP,
    const float4* __restrict__ s0, const float4* __restrict__ s1,
    const float4* __restrict__ s2, uint2* __restrict__ d0,
    uint2* __restrict__ d1, uint2* __restrict__ d2, int n4) {
  __shared__ int2 stg[CHUNK];             // 16 KB
  __shared__ unsigned short sbkt[CHUNK];  // 4 KB
  __shared__ int cnt[NBMAX];              // 2 KB
  __shared__ int cur[NBMAX];              // 2 KB
  __shared__ int gbase[NBMAX];            // 2 KB
  const int tid = threadIdx.x;

  if (blockIdx.x < P1_BLOCKS) {
    const int chunk = (nnz + P1_BLOCKS - 1) / P1_BLOCKS;
    const int s = blockIdx.x * chunk;
    const int e = min(nnz, s + chunk);
    const int n = e - s;
    if (n > 0) {
      p1_side(rows, cols, up_vals, s, n, shU, nbU, curU, regU, stg, sbkt,
              cnt, cur, gbase, tid);
      p1_side(cols, rows, pu_vals, s, n, shP, nbP, curP, regP, stg, sbkt,
              cnt, cur, gbase, tid);
    }
  } else {
    const int bid = blockIdx.x - P1_BLOCKS;
    const int stride = (gridDim.x - P1_BLOCKS) * 256;
    for (int i = bid * 256 + tid; i < 3 * n4; i += stride) {
      const int t = i / n4, j = i - t * n4;
      const float4* sp = (t == 0) ? s0 : ((t == 1) ? s1 : s2);
      uint2* dp = (t == 0) ? d0 : ((t == 1) ? d1 : d2);
      const float4 v = sp[j];
      uint2 o;
      o.x = f2bf(v.x) | (f2bf(v.y) << 16);
      o.y = f2bf(v.z) | (f2bf(v.w) << 16);
      dp[j] = o;
    }
  }
}

// ---------------------------------------------------------------------------
// Merged parallel exclusive scan of both bucket-total arrays (one block).
// ---------------------------------------------------------------------------
__device__ __forceinline__ void scan_one(const int* __restrict__ cnt,
                                         int* __restrict__ base, int nb,
                                         int* wsum) {
  const int tid = threadIdx.x;
  const int lane = tid & 63, wid = tid >> 6;
  const int v = (tid < nb) ? cnt[tid] : 0;
  int sc = v;
  for (int d = 1; d < 64; d <<= 1) {
    const int o = __shfl_up(sc, d);
    if (lane >= d) sc += o;
  }
  if (lane == 63) wsum[wid] = sc;
  __syncthreads();
  int woff = 0;
  for (int w = 0; w < wid; ++w) woff += wsum[w];
  if (tid < nb) base[tid] = woff + sc - v;
  __syncthreads();
}

__global__ __launch_bounds__(512) void bucket_scan2_kernel(
    const int* __restrict__ curU, int* __restrict__ baseU, int nbU,
    const int* __restrict__ curP, int* __restrict__ baseP, int nbP) {
  __shared__ int wsum[8];
  scan_one(curU, baseU, nbU, wsum);
  scan_one(curP, baseP, nbP, wsum);
}

// ---------------------------------------------------------------------------
// Merged bucket pass 2 (both sides): per-bucket LDS key histogram + scan ->
// compact ptr[] and final CSR payload scatter.
// ---------------------------------------------------------------------------
__global__ __launch_bounds__(256) void bucket_pass2_kernel(
    const int* __restrict__ curU, const int* __restrict__ baseU,
    const int2* __restrict__ regU, int* __restrict__ ptrU,
    int2* __restrict__ csrU, int nkeyU, int shU,
    const int* __restrict__ curP, const int* __restrict__ baseP,
    const int2* __restrict__ regP, int* __restrict__ ptrP,
    int2* __restrict__ csrP, int nkeyP, int shP, int nbU) {
  __shared__ int hist[NBMAX];
  const int tid = threadIdx.x;
  int b = blockIdx.x;
  const int* gCur;
  const int* gBase;
  const int2* reg;
  int* ptr;
  int2* csr;
  int nkey, sh;
  if (b < nbU) {
    gCur = curU; gBase = baseU; reg = regU; ptr = ptrU; csr = csrU;
    nkey = nkeyU; sh = shU;
  } else {
    b -= nbU;
    gCur = curP; gBase = baseP; reg = regP; ptr = ptrP; csr = csrP;
    nkey = nkeyP; sh = shP;
  }
  const int kpb = 1 << sh;
  const int n = min(gCur[b], RCAP);
  const int rb = b * RCAP;
  const int cb = gBase[b];
  const int keyLo = b << sh;
  for (int i = tid; i < kpb; i += 256) hist[i] = 0;
  __syncthreads();
  for (int i = tid; i < n; i += 256)
    atomicAdd(&hist[(unsigned)reg[rb + i].x >> 18], 1);
  __syncthreads();
  if (tid == 0) {
    int run = 0;
    for (int k = 0; k < kpb; ++k) {
      const int c = hist[k];
      hist[k] = run;
      run += c;
    }
  }
  __syncthreads();
  for (int k = tid; k < kpb; k += 256) {
    const int key = keyLo + k;
    if (key < nkey) ptr[key] = cb + hist[k];
  }
  __syncthreads();
  for (int i = tid; i < n; i += 256) {
    const int2 ent = reg[rb + i];
    const int k = (unsigned)ent.x >> 18;
    const int pos = atomicAdd(&hist[k], 1);
    csr[cb + pos] = make_int2(ent.x & 0x3FFFF, ent.y);
  }
}

// ---------------------------------------------------------------------------
// Per-user gather over bf16 tables -> bf16 g/s/p outputs [U][64].
// 16 lanes x 8B per row, 4 nnz per step (round-10 proven structure).
// ---------------------------------------------------------------------------
__global__ __launch_bounds__(256) void user_gather_kernel(
    const int* __restrict__ ptrU, const int2* __restrict__ csrU,
    const unsigned short* __restrict__ tblG,
    const unsigned short* __restrict__ tblS,
    const unsigned short* __restrict__ tblC,
    unsigned short* __restrict__ gw, unsigned short* __restrict__ sw,
    unsigned short* __restrict__ pw, int U, int nnz) {
  const int lane = threadIdx.x & 63;
  const int sub = lane >> 4, d4 = lane & 15;
  const int wv = blockIdx.x * 4 + (threadIdx.x >> 6);
  const int nW = gridDim.x * 4;
  for (int u = wv; u < U; u += nW) {
    const int start = ptrU[u];
    const int end = (u + 1 < U) ? ptrU[u + 1] : nnz;
    float4 g4 = {0, 0, 0, 0}, s4 = {0, 0, 0, 0}, p4 = {0, 0, 0, 0};
    for (int k0 = start; k0 < end; k0 += 64) {
      int c_v = 0;
      float v_v = 0.f;
      const int kk = k0 + lane;
      if (kk < end) {
        const int2 e = csrU[kk];
        c_v = e.x;
        v_v = __int_as_float(e.y);
      }
      const int steps = (min(64, end - k0) + 3) >> 2;
      for (int t = 0; t < steps; ++t) {
        const int src = t * 4 + sub;
        const int cc = __shfl(c_v, src);
        const float vv = __shfl(v_v, src);
        const size_t rb = (size_t)cc * EDIM;
        const uint2 gg = ((const uint2*)(tblG + rb))[d4];
        const uint2 ss = ((const uint2*)(tblS + rb))[d4];
        const uint2 pp = ((const uint2*)(tblC + rb))[d4];
        g4.x += vv * bflo(gg.x); g4.y += vv * bfhi(gg.x);
        g4.z += vv * bflo(gg.y); g4.w += vv * bfhi(gg.y);
        s4.x += vv * bflo(ss.x); s4.y += vv * bfhi(ss.x);
        s4.z += vv * bflo(ss.y); s4.w += vv * bfhi(ss.y);
        p4.x += vv * bflo(pp.x); p4.y += vv * bfhi(pp.x);
        p4.z += vv * bflo(pp.y); p4.w += vv * bfhi(pp.y);
      }
    }
#pragma unroll
    for (int m = 16; m <= 32; m <<= 1) {
      g4.x += __shfl_xor(g4.x, m); g4.y += __shfl_xor(g4.y, m);
      g4.z += __shfl_xor(g4.z, m); g4.w += __shfl_xor(g4.w, m);
      s4.x += __shfl_xor(s4.x, m); s4.y += __shfl_xor(s4.y, m);
      s4.z += __shfl_xor(s4.z, m); s4.w += __shfl_xor(s4.w, m);
      p4.x += __shfl_xor(p4.x, m); p4.y += __shfl_xor(p4.y, m);
      p4.z += __shfl_xor(p4.z, m); p4.w += __shfl_xor(p4.w, m);
    }
    if (sub == 0) {
      uint2 gp2, sp2, pp2;
      gp2.x = f2bf(g4.x) | (f2bf(g4.y) << 16);
      gp2.y = f2bf(g4.z) | (f2bf(g4.w) << 16);
      sp2.x = f2bf(s4.x) | (f2bf(s4.y) << 16);
      sp2.y = f2bf(s4.z) | (f2bf(s4.w) << 16);
      pp2.x = f2bf(p4.x) | (f2bf(p4.y) << 16);
      pp2.y = f2bf(p4.z) | (f2bf(p4.w) << 16);
      ((uint2*)(gw + (size_t)u * EDIM))[d4] = gp2;
      ((uint2*)(sw + (size_t)u * EDIM))[d4] = sp2;
      ((uint2*)(pw + (size_t)u * EDIM))[d4] = pp2;
    }
  }
}

// ---------------------------------------------------------------------------
// Fusion as bf16 MFMA GEMM: msg[U,448] @ W^T[448,64] + bias + gated merge.
// ---------------------------------------------------------------------------
#define FM_BLK 256
__global__ __launch_bounds__(FM_BLK) void fusion_mfma_kernel(
    const unsigned short* __restrict__ gbf, const unsigned short* __restrict__ sbf,
    const unsigned short* __restrict__ pbf, const float* __restrict__ uemb,
    const float* __restrict__ W, const float* __restrict__ b,
    unsigned short* __restrict__ hbf, int U) {
  __shared__ unsigned short wlds[7 * 2 * 4 * 64 * 8];  // 57344 B
  for (int fe = threadIdx.x; fe < 7 * 2 * 4 * 64; fe += FM_BLK) {
    const int ln = fe & 63;
    const int n = (fe >> 6) & 3;
    const int h = (fe >> 8) & 1;
    const int blk = fe >> 9;
    const int e = n * 16 + (ln & 15);
    const int f0 = blk * 64 + h * 32 + (ln >> 4) * 8;
    const float* wsrc = W + (size_t)e * 448 + f0;
    uint4 w4;
    w4.x = f2bf(wsrc[0]) | (f2bf(wsrc[1]) << 16);
    w4.y = f2bf(wsrc[2]) | (f2bf(wsrc[3]) << 16);
    w4.z = f2bf(wsrc[4]) | (f2bf(wsrc[5]) << 16);
    w4.w = f2bf(wsrc[6]) | (f2bf(wsrc[7]) << 16);
    ((uint4*)wlds)[fe] = w4;
  }
  __syncthreads();

  const int l = threadIdx.x & 63;
  const int row16 = l & 15, kg = l >> 4;
  const int wv = blockIdx.x * (FM_BLK / 64) + (threadIdx.x >> 6);
  const int nWv = gridDim.x * (FM_BLK / 64);
  float bias4[4];
#pragma unroll
  for (int n = 0; n < 4; ++n) bias4[n] = b[n * 16 + row16];

  const int nT = (U + 15) >> 4;
  for (int t = wv; t < nT; t += nWv) {
    const int u0 = t * 16;
    f32x4 acc0 = {0, 0, 0, 0}, acc1 = {0, 0, 0, 0};
    f32x4 acc2 = {0, 0, 0, 0}, acc3 = {0, 0, 0, 0};
    const int ua = min(u0 + row16, U - 1);  // clamped A-row user
#pragma unroll
    for (int h = 0; h < 2; ++h) {
      const size_t off = (size_t)ua * EDIM + h * 32 + kg * 8;
      short8 gfr = *(const short8*)(gbf + off);
      short8 sfr = *(const short8*)(sbf + off);
      short8 pfr = *(const short8*)(pbf + off);
      float gf[8], sf[8], pf[8];
#pragma unroll
      for (int j = 0; j < 8; ++j) {
        gf[j] = bf2f((unsigned short)gfr[j]);
        sf[j] = bf2f((unsigned short)sfr[j]);
        pf[j] = bf2f((unsigned short)pfr[j]);
      }
      short8 gs, gp, sp, gsp;
#pragma unroll
      for (int j = 0; j < 8; ++j) {
        const float a = gf[j] * sf[j];
        gs[j] = (short)f2bf(a);
        gp[j] = (short)f2bf(gf[j] * pf[j]);
        sp[j] = (short)f2bf(sf[j] * pf[j]);
        gsp[j] = (short)f2bf(a * pf[j]);
      }
      short8 afr[7] = {gfr, sfr, pfr, gs, gp, sp, gsp};
#pragma unroll
      for (int blk = 0; blk < 7; ++blk) {
        const int fb = blk * 512 + h * 256;
        const short8 b0 = *(const short8*)(wlds + (size_t)(fb + 0 * 64 + l) * 8);
        const short8 b1 = *(const short8*)(wlds + (size_t)(fb + 1 * 64 + l) * 8);
        const short8 b2 = *(const short8*)(wlds + (size_t)(fb + 2 * 64 + l) * 8);
        const short8 b3 = *(const short8*)(wlds + (size_t)(fb + 3 * 64 + l) * 8);
        acc0 = __builtin_amdgcn_mfma_f32_16x16x32_bf16(afr[blk], b0, acc0, 0, 0, 0);
        acc1 = __builtin_amdgcn_mfma_f32_16x16x32_bf16(afr[blk], b1, acc1, 0, 0, 0);
        acc2 = __builtin_amdgcn_mfma_f32_16x16x32_bf16(afr[blk], b2, acc2, 0, 0, 0);
        acc3 = __builtin_amdgcn_mfma_f32_16x16x32_bf16(afr[blk], b3, acc3, 0, 0, 0);
      }
    }
#pragma unroll
    for (int r = 0; r < 4; ++r) {
      const int u = u0 + kg * 4 + r;
      if (u < U) {
        const size_t ubase = (size_t)u * EDIM + row16;
        {
          const float me = acc0[r] + bias4[0];
          const float ue = uemb[ubase + 0];
          hbf[ubase + 0] = (unsigned short)f2bf(me + ue + me * ue);
        }
        {
          const float me = acc1[r] + bias4[1];
          const float ue = uemb[ubase + 16];
          hbf[ubase + 16] = (unsigned short)f2bf(me + ue + me * ue);
        }
        {
          const float me = acc2[r] + bias4[2];
          const float ue = uemb[ubase + 32];
          hbf[ubase + 32] = (unsigned short)f2bf(me + ue + me * ue);
        }
        {
          const float me = acc3[r] + bias4[3];
          const float ue = uemb[ubase + 48];
          hbf[ubase + 48] = (unsigned short)f2bf(me + ue + me * ue);
        }
      }
    }
  }
}

// ---------------------------------------------------------------------------
// Per-POI gather over bf16 hg with 4-deep load pipeline. csrP = {row,
// pu_val}; fused mean: out = init + (L/2)*acc.
// ---------------------------------------------------------------------------
__global__ __launch_bounds__(256) void poi_gather_kernel(
    const int* __restrict__ ptrP, const int2* __restrict__ csrP,
    const unsigned short* __restrict__ hbf, const float* __restrict__ init,
    const int* __restrict__ num_layers, float* __restrict__ out, int P,
    int nnz) {
  const float scale = 0.5f * (float)num_layers[0];
  const int lane = threadIdx.x & 63;
  const int sub = lane >> 4, d4 = lane & 15;
  const int wv = blockIdx.x * 4 + (threadIdx.x >> 6);
  const int nW = gridDim.x * 4;
  for (int c = wv; c < P; c += nW) {
    const int start = ptrP[c];
    const int end = (c + 1 < P) ? ptrP[c + 1] : nnz;
    float4 a4 = {0, 0, 0, 0};
    for (int k0 = start; k0 < end; k0 += 64) {
      int r_v = 0;
      float v_v = 0.f;
      const int kk = k0 + lane;
      if (kk < end) {
        const int2 e = csrP[kk];
        r_v = e.x;
        v_v = __int_as_float(e.y);
      }
      const int steps = (min(64, end - k0) + 3) >> 2;
      for (int t0 = 0; t0 < steps; t0 += 4) {
        uint2 h[4];
        float vq[4];
#pragma unroll
        for (int q = 0; q < 4; ++q) {
          const int src = ((t0 + q) * 4 + sub) & 63;
          const int rr = __shfl(r_v, src);
          vq[q] = __shfl(v_v, src);
          h[q] = ((const uint2*)(hbf + (size_t)rr * EDIM))[d4];
        }
#pragma unroll
        for (int q = 0; q < 4; ++q) {
          a4.x += vq[q] * bflo(h[q].x);
          a4.y += vq[q] * bfhi(h[q].x);
          a4.z += vq[q] * bflo(h[q].y);
          a4.w += vq[q] * bfhi(h[q].y);
        }
      }
    }
#pragma unroll
    for (int m = 16; m <= 32; m <<= 1) {
      a4.x += __shfl_xor(a4.x, m); a4.y += __shfl_xor(a4.y, m);
      a4.z += __shfl_xor(a4.z, m); a4.w += __shfl_xor(a4.w, m);
    }
    if (sub == 0) {
      const float4 iv = ((const float4*)(init + (size_t)c * EDIM))[d4];
      float4 o;
      o.x = iv.x + scale * a4.x;
      o.y = iv.y + scale * a4.y;
      o.z = iv.z + scale * a4.z;
      o.w = iv.w + scale * a4.w;
      ((float4*)(out + (size_t)c * EDIM))[d4] = o;
    }
  }
}

extern "C" void kernel_launch(void* const* d_in, const int* in_sizes, int n_in,
                              void* d_out, int out_size, void* d_ws,
                              size_t ws_size, hipStream_t stream) {
  const float* init = (const float*)d_in[0];
  const float* colp = (const float*)d_in[1];
  const float* geo = (const float*)d_in[2];
  const float* seq = (const float*)d_in[3];
  const float* uemb = (const float*)d_in[4];
  const int* up_rows = (const int*)d_in[5];
  const int* up_cols = (const int*)d_in[6];
  const float* up_vals = (const float*)d_in[7];
  const float* pu_vals = (const float*)d_in[8];
  const float* W = (const float*)d_in[9];
  const float* b = (const float*)d_in[10];
  const int* num_layers = (const int*)d_in[11];

  const int U = in_sizes[4] / EDIM;   // 100000 users
  const int P = in_sizes[0] / EDIM;   // 200000 POIs
  const int NNZ = in_sizes[5];

  const int SHU = 8, SHP = 9;                 // 256 users / 512 POIs per bucket
  const int NBU = (U + 255) >> 8;             // 391
  const int NBP = (P + 511) >> 9;             // 391

  // ---- workspace layout (~97 MB) ----
  int* ptrU = (int*)d_ws;                     // U (0.4 MB)
  int* ptrP = ptrU + U;                       // P (0.8 MB)
  int* curU = ptrP + P;                       // 512
  int* curP = curU + NBMAX;                   // 512
  int* baseU = curP + NBMAX;                  // 512
  int* baseP = baseU + NBMAX;                 // 512
  int2* csrP = (int2*)(baseP + NBMAX);        // NNZ {row, pu_val} (16 MB)
  int2* csrU = csrP + NNZ;                    // NNZ {col, up_val} (16 MB)
  unsigned short* tblS = (unsigned short*)(csrU + NNZ);  // P*64 bf16 (25.6 MB)
  unsigned short* gbf = tblS + (size_t)P * EDIM;         // U*64 bf16 (12.8 MB)
  unsigned short* sbf = gbf + (size_t)U * EDIM;          // 12.8 MB
  unsigned short* pbf = sbf + (size_t)U * EDIM;          // 12.8 MB
  // hbf (12.8 MB) overlays csrU (16 MB, dead after user_gather)
  unsigned short* hbf = (unsigned short*)csrU;
  // bucket regions (2 x 391*6144 int2 = 38.4 MB) overlay gbf..pbf (38.4 MB,
  // dead until user_gather writes them after pass2 is done)
  int2* regU = (int2*)gbf;
  int2* regP = regU + (size_t)NBU * RCAP;
  // d_out scratch: two bf16 tables (dead before final out write)
  unsigned short* tblG = (unsigned short*)d_out;          // P*64
  unsigned short* tblC = tblG + (size_t)P * EDIM;         // P*64
  float* out = (float*)d_out;

  hipMemsetAsync(curU, 0, 2 * NBMAX * sizeof(int), stream);

  prep_kernel<<<P1_BLOCKS + 2048, 256, 0, stream>>>(
      up_rows, up_cols, up_vals, pu_vals, curU, curP, regU, regP, NNZ, SHU,
      SHP, NBU, NBP, (const float4*)geo, (const float4*)seq,
      (const float4*)colp, (uint2*)tblG, (uint2*)tblS, (uint2*)tblC,
      P * (EDIM / 4));

  bucket_scan2_kernel<<<1, 512, 0, stream>>>(curU, baseU, NBU, curP, baseP,
                                             NBP);

  bucket_pass2_kernel<<<NBU + NBP, 256, 0, stream>>>(
      curU, baseU, regU, ptrU, csrU, U, SHU, curP, baseP, regP, ptrP, csrP, P,
      SHP, NBU);

  user_gather_kernel<<<2048, 256, 0, stream>>>(ptrU, csrU, tblG, tblS, tblC,
                                               gbf, sbf, pbf, U, NNZ);

  fusion_mfma_kernel<<<512, FM_BLK, 0, stream>>>(gbf, sbf, pbf, uemb, W, b,
                                                 hbf, U);

  poi_gather_kernel<<<2048, 256, 0, stream>>>(ptrP, csrP, hbf, init,
                                              num_layers, out, P, NNZ);
}

// Round 17
// 392.975 us; speedup vs baseline: 1.0764x; 1.0181x over previous
//
#include <hip/hip_runtime.h>

#define EDIM 64
#define RCAP 6144    // per-bucket region capacity (mean ~5115, +14 sigma)
#define NBMAX 512
#define P1_BLOCKS 1024
#define CHUNK 2048   // >= ceil(NNZ / P1_BLOCKS)

typedef __attribute__((ext_vector_type(8))) short short8;
typedef __attribute__((ext_vector_type(4))) float f32x4;

// f32 -> bf16 round-to-nearest-even
__device__ __forceinline__ unsigned int f2bf(float x) {
  unsigned int u = __float_as_uint(x);
  u += 0x7FFFu + ((u >> 16) & 1u);
  return u >> 16;
}
__device__ __forceinline__ float bflo(unsigned int u) {
  return __uint_as_float(u << 16);
}
__device__ __forceinline__ float bfhi(unsigned int u) {
  return __uint_as_float(u & 0xFFFF0000u);
}
__device__ __forceinline__ float bf2f(unsigned short s) {
  return __uint_as_float(((unsigned int)s) << 16);
}

// ---------------------------------------------------------------------------
// Parallel exclusive scan of cnt[0..nb) -> cur[0..nb), nb <= 512, 256 thr.
// Thread tid owns elements {2*tid, 2*tid+1}; wave-scan of pair sums.
// ---------------------------------------------------------------------------
__device__ __forceinline__ void lds_excl_scan(const int* __restrict__ cnt,
                                              int* __restrict__ cur, int nb,
                                              int* wpart, int tid) {
  const int lane = tid & 63, wid = tid >> 6;
  const int i0 = tid * 2, i1 = i0 + 1;
  const int a = (i0 < nb) ? cnt[i0] : 0;
  const int b = (i1 < nb) ? cnt[i1] : 0;
  const int s = a + b;
  int sc = s;
  for (int d = 1; d < 64; d <<= 1) {
    const int o = __shfl_up(sc, d);
    if (lane >= d) sc += o;
  }
  if (lane == 63) wpart[wid] = sc;
  __syncthreads();
  int woff = 0;
  for (int w = 0; w < wid; ++w) woff += wpart[w];
  const int excl = woff + sc - s;
  if (i0 < nb) cur[i0] = excl;
  if (i1 < nb) cur[i1] = excl + a;
  __syncthreads();
}

// ---------------------------------------------------------------------------
// One side of sorted pass1: LDS histogram -> parallel LDS scan -> global
// range reserve -> LDS counting-sort scatter -> run-coalesced writeout.
// ---------------------------------------------------------------------------
__device__ __forceinline__ void p1_side(
    const int* __restrict__ keys, const int* __restrict__ pay,
    const float* __restrict__ vals, int s, int n, int sh, int nb,
    int* __restrict__ curG, int2* __restrict__ reg, int2* stg,
    unsigned short* sbkt, int* cnt, int* cur, int* gbase, int* wpart,
    int tid) {
  for (int i = tid; i < nb; i += 256) cnt[i] = 0;
  __syncthreads();
  for (int i = tid; i < n; i += 256) atomicAdd(&cnt[keys[s + i] >> sh], 1);
  __syncthreads();
  lds_excl_scan(cnt, cur, nb, wpart, tid);
  for (int b = tid; b < nb; b += 256) {
    const int c = cnt[b];
    gbase[b] = c ? atomicAdd(&curG[b], c) : 0;
  }
  __syncthreads();
  const int mask = (1 << sh) - 1;
  for (int i = tid; i < n; i += 256) {
    const int k = keys[s + i];
    const int b = k >> sh;
    const int pos = atomicAdd(&cur[b], 1);
    stg[pos] = make_int2(pay[s + i] | ((k & mask) << 18),
                         __float_as_int(vals[s + i]));
    sbkt[pos] = (unsigned short)b;
  }
  __syncthreads();
  // cur[b] == ldsBase[b] + cnt[b]; cnt intact -> ldsBase = cur - cnt.
  for (int j = tid; j < n; j += 256) {
    const int b = sbkt[j];
    const int off = gbase[b] + (j - (cur[b] - cnt[b]));
    if (off < RCAP) reg[b * RCAP + off] = stg[j];
  }
  __syncthreads();
}

// ---------------------------------------------------------------------------
// Fused prep: blocks [0, P1_BLOCKS) run SORTED bucket pass 1 (run-coalesced
// region writes); remaining blocks run the f32->bf16 table conversion.
// ---------------------------------------------------------------------------
__global__ __launch_bounds__(256) void prep_kernel(
    const int* __restrict__ rows, const int* __restrict__ cols,
    const float* __restrict__ up_vals, const float* __restrict__ pu_vals,
    int* __restrict__ curU, int* __restrict__ curP,
    int2* __restrict__ regU, int2* __restrict__ regP,
    int nnz, int shU, int shP, int nbU, int nbP,
    const float4* __restrict__ s0, const float4* __restrict__ s1,
    const float4* __restrict__ s2, uint2* __restrict__ d0,
    uint2* __restrict__ d1, uint2* __restrict__ d2, int n4) {
  __shared__ int2 stg[CHUNK];             // 16 KB
  __shared__ unsigned short sbkt[CHUNK];  // 4 KB
  __shared__ int cnt[NBMAX];              // 2 KB
  __shared__ int cur[NBMAX];              // 2 KB
  __shared__ int gbase[NBMAX];            // 2 KB
  __shared__ int wpart[4];
  const int tid = threadIdx.x;

  if (blockIdx.x < P1_BLOCKS) {
    const int chunk = (nnz + P1_BLOCKS - 1) / P1_BLOCKS;
    const int s = blockIdx.x * chunk;
    const int e = min(nnz, s + chunk);
    const int n = e - s;
    if (n > 0) {
      p1_side(rows, cols, up_vals, s, n, shU, nbU, curU, regU, stg, sbkt,
              cnt, cur, gbase, wpart, tid);
      p1_side(cols, rows, pu_vals, s, n, shP, nbP, curP, regP, stg, sbkt,
              cnt, cur, gbase, wpart, tid);
    }
  } else {
    const int bid = blockIdx.x - P1_BLOCKS;
    const int stride = (gridDim.x - P1_BLOCKS) * 256;
    for (int i = bid * 256 + tid; i < 3 * n4; i += stride) {
      const int t = i / n4, j = i - t * n4;
      const float4* sp = (t == 0) ? s0 : ((t == 1) ? s1 : s2);
      uint2* dp = (t == 0) ? d0 : ((t == 1) ? d1 : d2);
      const float4 v = sp[j];
      uint2 o;
      o.x = f2bf(v.x) | (f2bf(v.y) << 16);
      o.y = f2bf(v.z) | (f2bf(v.w) << 16);
      dp[j] = o;
    }
  }
}

// ---------------------------------------------------------------------------
// Merged parallel exclusive scan of both bucket-total arrays (one block).
// ---------------------------------------------------------------------------
__device__ __forceinline__ void scan_one(const int* __restrict__ cnt,
                                         int* __restrict__ base, int nb,
                                         int* wsum) {
  const int tid = threadIdx.x;
  const int lane = tid & 63, wid = tid >> 6;
  const int v = (tid < nb) ? cnt[tid] : 0;
  int sc = v;
  for (int d = 1; d < 64; d <<= 1) {
    const int o = __shfl_up(sc, d);
    if (lane >= d) sc += o;
  }
  if (lane == 63) wsum[wid] = sc;
  __syncthreads();
  int woff = 0;
  for (int w = 0; w < wid; ++w) woff += wsum[w];
  if (tid < nb) base[tid] = woff + sc - v;
  __syncthreads();
}

__global__ __launch_bounds__(512) void bucket_scan2_kernel(
    const int* __restrict__ curU, int* __restrict__ baseU, int nbU,
    const int* __restrict__ curP, int* __restrict__ baseP, int nbP) {
  __shared__ int wsum[8];
  scan_one(curU, baseU, nbU, wsum);
  scan_one(curP, baseP, nbP, wsum);
}

// ---------------------------------------------------------------------------
// Merged bucket pass 2 (both sides): per-bucket LDS key histogram + scan ->
// compact ptr[] and final CSR payload scatter.
// ---------------------------------------------------------------------------
__global__ __launch_bounds__(256) void bucket_pass2_kernel(
    const int* __restrict__ curU, const int* __restrict__ baseU,
    const int2* __restrict__ regU, int* __restrict__ ptrU,
    int2* __restrict__ csrU, int nkeyU, int shU,
    const int* __restrict__ curP, const int* __restrict__ baseP,
    const int2* __restrict__ regP, int* __restrict__ ptrP,
    int2* __restrict__ csrP, int nkeyP, int shP, int nbU) {
  __shared__ int hist[NBMAX];
  const int tid = threadIdx.x;
  int b = blockIdx.x;
  const int* gCur;
  const int* gBase;
  const int2* reg;
  int* ptr;
  int2* csr;
  int nkey, sh;
  if (b < nbU) {
    gCur = curU; gBase = baseU; reg = regU; ptr = ptrU; csr = csrU;
    nkey = nkeyU; sh = shU;
  } else {
    b -= nbU;
    gCur = curP; gBase = baseP; reg = regP; ptr = ptrP; csr = csrP;
    nkey = nkeyP; sh = shP;
  }
  const int kpb = 1 << sh;
  const int n = min(gCur[b], RCAP);
  const int rb = b * RCAP;
  const int cb = gBase[b];
  const int keyLo = b << sh;
  for (int i = tid; i < kpb; i += 256) hist[i] = 0;
  __syncthreads();
  for (int i = tid; i < n; i += 256)
    atomicAdd(&hist[(unsigned)reg[rb + i].x >> 18], 1);
  __syncthreads();
  if (tid == 0) {
    int run = 0;
    for (int k = 0; k < kpb; ++k) {
      const int c = hist[k];
      hist[k] = run;
      run += c;
    }
  }
  __syncthreads();
  for (int k = tid; k < kpb; k += 256) {
    const int key = keyLo + k;
    if (key < nkey) ptr[key] = cb + hist[k];
  }
  __syncthreads();
  for (int i = tid; i < n; i += 256) {
    const int2 ent = reg[rb + i];
    const int k = (unsigned)ent.x >> 18;
    const int pos = atomicAdd(&hist[k], 1);
    csr[cb + pos] = make_int2(ent.x & 0x3FFFF, ent.y);
  }
}

// ---------------------------------------------------------------------------
// Per-user gather over bf16 tables -> bf16 g/s/p outputs [U][64].
// 16 lanes x 8B per row, 4 nnz per step (round-10 proven structure).
// ---------------------------------------------------------------------------
__global__ __launch_bounds__(256) void user_gather_kernel(
    const int* __restrict__ ptrU, const int2* __restrict__ csrU,
    const unsigned short* __restrict__ tblG,
    const unsigned short* __restrict__ tblS,
    const unsigned short* __restrict__ tblC,
    unsigned short* __restrict__ gw, unsigned short* __restrict__ sw,
    unsigned short* __restrict__ pw, int U, int nnz) {
  const int lane = threadIdx.x & 63;
  const int sub = lane >> 4, d4 = lane & 15;
  const int wv = blockIdx.x * 4 + (threadIdx.x >> 6);
  const int nW = gridDim.x * 4;
  for (int u = wv; u < U; u += nW) {
    const int start = ptrU[u];
    const int end = (u + 1 < U) ? ptrU[u + 1] : nnz;
    float4 g4 = {0, 0, 0, 0}, s4 = {0, 0, 0, 0}, p4 = {0, 0, 0, 0};
    for (int k0 = start; k0 < end; k0 += 64) {
      int c_v = 0;
      float v_v = 0.f;
      const int kk = k0 + lane;
      if (kk < end) {
        const int2 e = csrU[kk];
        c_v = e.x;
        v_v = __int_as_float(e.y);
      }
      const int steps = (min(64, end - k0) + 3) >> 2;
      for (int t = 0; t < steps; ++t) {
        const int src = t * 4 + sub;
        const int cc = __shfl(c_v, src);
        const float vv = __shfl(v_v, src);
        const size_t rb = (size_t)cc * EDIM;
        const uint2 gg = ((const uint2*)(tblG + rb))[d4];
        const uint2 ss = ((const uint2*)(tblS + rb))[d4];
        const uint2 pp = ((const uint2*)(tblC + rb))[d4];
        g4.x += vv * bflo(gg.x); g4.y += vv * bfhi(gg.x);
        g4.z += vv * bflo(gg.y); g4.w += vv * bfhi(gg.y);
        s4.x += vv * bflo(ss.x); s4.y += vv * bfhi(ss.x);
        s4.z += vv * bflo(ss.y); s4.w += vv * bfhi(ss.y);
        p4.x += vv * bflo(pp.x); p4.y += vv * bfhi(pp.x);
        p4.z += vv * bflo(pp.y); p4.w += vv * bfhi(pp.y);
      }
    }
#pragma unroll
    for (int m = 16; m <= 32; m <<= 1) {
      g4.x += __shfl_xor(g4.x, m); g4.y += __shfl_xor(g4.y, m);
      g4.z += __shfl_xor(g4.z, m); g4.w += __shfl_xor(g4.w, m);
      s4.x += __shfl_xor(s4.x, m); s4.y += __shfl_xor(s4.y, m);
      s4.z += __shfl_xor(s4.z, m); s4.w += __shfl_xor(s4.w, m);
      p4.x += __shfl_xor(p4.x, m); p4.y += __shfl_xor(p4.y, m);
      p4.z += __shfl_xor(p4.z, m); p4.w += __shfl_xor(p4.w, m);
    }
    if (sub == 0) {
      uint2 gp2, sp2, pp2;
      gp2.x = f2bf(g4.x) | (f2bf(g4.y) << 16);
      gp2.y = f2bf(g4.z) | (f2bf(g4.w) << 16);
      sp2.x = f2bf(s4.x) | (f2bf(s4.y) << 16);
      sp2.y = f2bf(s4.z) | (f2bf(s4.w) << 16);
      pp2.x = f2bf(p4.x) | (f2bf(p4.y) << 16);
      pp2.y = f2bf(p4.z) | (f2bf(p4.w) << 16);
      ((uint2*)(gw + (size_t)u * EDIM))[d4] = gp2;
      ((uint2*)(sw + (size_t)u * EDIM))[d4] = sp2;
      ((uint2*)(pw + (size_t)u * EDIM))[d4] = pp2;
    }
  }
}

// ---------------------------------------------------------------------------
// Fusion as bf16 MFMA GEMM: msg[U,448] @ W^T[448,64] + bias + gated merge.
// ---------------------------------------------------------------------------
#define FM_BLK 256
__global__ __launch_bounds__(FM_BLK) void fusion_mfma_kernel(
    const unsigned short* __restrict__ gbf, const unsigned short* __restrict__ sbf,
    const unsigned short* __restrict__ pbf, const float* __restrict__ uemb,
    const float* __restrict__ W, const float* __restrict__ b,
    unsigned short* __restrict__ hbf, int U) {
  __shared__ unsigned short wlds[7 * 2 * 4 * 64 * 8];  // 57344 B
  for (int fe = threadIdx.x; fe < 7 * 2 * 4 * 64; fe += FM_BLK) {
    const int ln = fe & 63;
    const int n = (fe >> 6) & 3;
    const int h = (fe >> 8) & 1;
    const int blk = fe >> 9;
    const int e = n * 16 + (ln & 15);
    const int f0 = blk * 64 + h * 32 + (ln >> 4) * 8;
    const float* wsrc = W + (size_t)e * 448 + f0;
    uint4 w4;
    w4.x = f2bf(wsrc[0]) | (f2bf(wsrc[1]) << 16);
    w4.y = f2bf(wsrc[2]) | (f2bf(wsrc[3]) << 16);
    w4.z = f2bf(wsrc[4]) | (f2bf(wsrc[5]) << 16);
    w4.w = f2bf(wsrc[6]) | (f2bf(wsrc[7]) << 16);
    ((uint4*)wlds)[fe] = w4;
  }
  __syncthreads();

  const int l = threadIdx.x & 63;
  const int row16 = l & 15, kg = l >> 4;
  const int wv = blockIdx.x * (FM_BLK / 64) + (threadIdx.x >> 6);
  const int nWv = gridDim.x * (FM_BLK / 64);
  float bias4[4];
#pragma unroll
  for (int n = 0; n < 4; ++n) bias4[n] = b[n * 16 + row16];

  const int nT = (U + 15) >> 4;
  for (int t = wv; t < nT; t += nWv) {
    const int u0 = t * 16;
    f32x4 acc0 = {0, 0, 0, 0}, acc1 = {0, 0, 0, 0};
    f32x4 acc2 = {0, 0, 0, 0}, acc3 = {0, 0, 0, 0};
    const int ua = min(u0 + row16, U - 1);  // clamped A-row user
#pragma unroll
    for (int h = 0; h < 2; ++h) {
      const size_t off = (size_t)ua * EDIM + h * 32 + kg * 8;
      short8 gfr = *(const short8*)(gbf + off);
      short8 sfr = *(const short8*)(sbf + off);
      short8 pfr = *(const short8*)(pbf + off);
      float gf[8], sf[8], pf[8];
#pragma unroll
      for (int j = 0; j < 8; ++j) {
        gf[j] = bf2f((unsigned short)gfr[j]);
        sf[j] = bf2f((unsigned short)sfr[j]);
        pf[j] = bf2f((unsigned short)pfr[j]);
      }
      short8 gs, gp, sp, gsp;
#pragma unroll
      for (int j = 0; j < 8; ++j) {
        const float a = gf[j] * sf[j];
        gs[j] = (short)f2bf(a);
        gp[j] = (short)f2bf(gf[j] * pf[j]);
        sp[j] = (short)f2bf(sf[j] * pf[j]);
        gsp[j] = (short)f2bf(a * pf[j]);
      }
      short8 afr[7] = {gfr, sfr, pfr, gs, gp, sp, gsp};
#pragma unroll
      for (int blk = 0; blk < 7; ++blk) {
        const int fb = blk * 512 + h * 256;
        const short8 b0 = *(const short8*)(wlds + (size_t)(fb + 0 * 64 + l) * 8);
        const short8 b1 = *(const short8*)(wlds + (size_t)(fb + 1 * 64 + l) * 8);
        const short8 b2 = *(const short8*)(wlds + (size_t)(fb + 2 * 64 + l) * 8);
        const short8 b3 = *(const short8*)(wlds + (size_t)(fb + 3 * 64 + l) * 8);
        acc0 = __builtin_amdgcn_mfma_f32_16x16x32_bf16(afr[blk], b0, acc0, 0, 0, 0);
        acc1 = __builtin_amdgcn_mfma_f32_16x16x32_bf16(afr[blk], b1, acc1, 0, 0, 0);
        acc2 = __builtin_amdgcn_mfma_f32_16x16x32_bf16(afr[blk], b2, acc2, 0, 0, 0);
        acc3 = __builtin_amdgcn_mfma_f32_16x16x32_bf16(afr[blk], b3, acc3, 0, 0, 0);
      }
    }
#pragma unroll
    for (int r = 0; r < 4; ++r) {
      const int u = u0 + kg * 4 + r;
      if (u < U) {
        const size_t ubase = (size_t)u * EDIM + row16;
        {
          const float me = acc0[r] + bias4[0];
          const float ue = uemb[ubase + 0];
          hbf[ubase + 0] = (unsigned short)f2bf(me + ue + me * ue);
        }
        {
          const float me = acc1[r] + bias4[1];
          const float ue = uemb[ubase + 16];
          hbf[ubase + 16] = (unsigned short)f2bf(me + ue + me * ue);
        }
        {
          const float me = acc2[r] + bias4[2];
          const float ue = uemb[ubase + 32];
          hbf[ubase + 32] = (unsigned short)f2bf(me + ue + me * ue);
        }
        {
          const float me = acc3[r] + bias4[3];
          const float ue = uemb[ubase + 48];
          hbf[ubase + 48] = (unsigned short)f2bf(me + ue + me * ue);
        }
      }
    }
  }
}

// ---------------------------------------------------------------------------
// Per-POI gather over bf16 hg with 4-deep load pipeline. csrP = {row,
// pu_val}; fused mean: out = init + (L/2)*acc.
// ---------------------------------------------------------------------------
__global__ __launch_bounds__(256) void poi_gather_kernel(
    const int* __restrict__ ptrP, const int2* __restrict__ csrP,
    const unsigned short* __restrict__ hbf, const float* __restrict__ init,
    const int* __restrict__ num_layers, float* __restrict__ out, int P,
    int nnz) {
  const float scale = 0.5f * (float)num_layers[0];
  const int lane = threadIdx.x & 63;
  const int sub = lane >> 4, d4 = lane & 15;
  const int wv = blockIdx.x * 4 + (threadIdx.x >> 6);
  const int nW = gridDim.x * 4;
  for (int c = wv; c < P; c += nW) {
    const int start = ptrP[c];
    const int end = (c + 1 < P) ? ptrP[c + 1] : nnz;
    float4 a4 = {0, 0, 0, 0};
    for (int k0 = start; k0 < end; k0 += 64) {
      int r_v = 0;
      float v_v = 0.f;
      const int kk = k0 + lane;
      if (kk < end) {
        const int2 e = csrP[kk];
        r_v = e.x;
        v_v = __int_as_float(e.y);
      }
      const int steps = (min(64, end - k0) + 3) >> 2;
      for (int t0 = 0; t0 < steps; t0 += 4) {
        uint2 h[4];
        float vq[4];
#pragma unroll
        for (int q = 0; q < 4; ++q) {
          const int src = ((t0 + q) * 4 + sub) & 63;
          const int rr = __shfl(r_v, src);
          vq[q] = __shfl(v_v, src);
          h[q] = ((const uint2*)(hbf + (size_t)rr * EDIM))[d4];
        }
#pragma unroll
        for (int q = 0; q < 4; ++q) {
          a4.x += vq[q] * bflo(h[q].x);
          a4.y += vq[q] * bfhi(h[q].x);
          a4.z += vq[q] * bflo(h[q].y);
          a4.w += vq[q] * bfhi(h[q].y);
        }
      }
    }
#pragma unroll
    for (int m = 16; m <= 32; m <<= 1) {
      a4.x += __shfl_xor(a4.x, m); a4.y += __shfl_xor(a4.y, m);
      a4.z += __shfl_xor(a4.z, m); a4.w += __shfl_xor(a4.w, m);
    }
    if (sub == 0) {
      const float4 iv = ((const float4*)(init + (size_t)c * EDIM))[d4];
      float4 o;
      o.x = iv.x + scale * a4.x;
      o.y = iv.y + scale * a4.y;
      o.z = iv.z + scale * a4.z;
      o.w = iv.w + scale * a4.w;
      ((float4*)(out + (size_t)c * EDIM))[d4] = o;
    }
  }
}

extern "C" void kernel_launch(void* const* d_in, const int* in_sizes, int n_in,
                              void* d_out, int out_size, void* d_ws,
                              size_t ws_size, hipStream_t stream) {
  const float* init = (const float*)d_in[0];
  const float* colp = (const float*)d_in[1];
  const float* geo = (const float*)d_in[2];
  const float* seq = (const float*)d_in[3];
  const float* uemb = (const float*)d_in[4];
  const int* up_rows = (const int*)d_in[5];
  const int* up_cols = (const int*)d_in[6];
  const float* up_vals = (const float*)d_in[7];
  const float* pu_vals = (const float*)d_in[8];
  const float* W = (const float*)d_in[9];
  const float* b = (const float*)d_in[10];
  const int* num_layers = (const int*)d_in[11];

  const int U = in_sizes[4] / EDIM;   // 100000 users
  const int P = in_sizes[0] / EDIM;   // 200000 POIs
  const int NNZ = in_sizes[5];

  const int SHU = 8, SHP = 9;                 // 256 users / 512 POIs per bucket
  const int NBU = (U + 255) >> 8;             // 391
  const int NBP = (P + 511) >> 9;             // 391

  // ---- workspace layout (~97 MB) ----
  int* ptrU = (int*)d_ws;                     // U (0.4 MB)
  int* ptrP = ptrU + U;                       // P (0.8 MB)
  int* curU = ptrP + P;                       // 512
  int* curP = curU + NBMAX;                   // 512
  int* baseU = curP + NBMAX;                  // 512
  int* baseP = baseU + NBMAX;                 // 512
  int2* csrP = (int2*)(baseP + NBMAX);        // NNZ {row, pu_val} (16 MB)
  int2* csrU = csrP + NNZ;                    // NNZ {col, up_val} (16 MB)
  unsigned short* tblS = (unsigned short*)(csrU + NNZ);  // P*64 bf16 (25.6 MB)
  unsigned short* gbf = tblS + (size_t)P * EDIM;         // U*64 bf16 (12.8 MB)
  unsigned short* sbf = gbf + (size_t)U * EDIM;          // 12.8 MB
  unsigned short* pbf = sbf + (size_t)U * EDIM;          // 12.8 MB
  // hbf (12.8 MB) overlays csrU (16 MB, dead after user_gather)
  unsigned short* hbf = (unsigned short*)csrU;
  // bucket regions (2 x 391*6144 int2 = 38.4 MB) overlay gbf..pbf (38.4 MB,
  // dead until user_gather writes them after pass2 is done)
  int2* regU = (int2*)gbf;
  int2* regP = regU + (size_t)NBU * RCAP;
  // d_out scratch: two bf16 tables (dead before final out write)
  unsigned short* tblG = (unsigned short*)d_out;          // P*64
  unsigned short* tblC = tblG + (size_t)P * EDIM;         // P*64
  float* out = (float*)d_out;

  hipMemsetAsync(curU, 0, 2 * NBMAX * sizeof(int), stream);

  prep_kernel<<<P1_BLOCKS + 2048, 256, 0, stream>>>(
      up_rows, up_cols, up_vals, pu_vals, curU, curP, regU, regP, NNZ, SHU,
      SHP, NBU, NBP, (const float4*)geo, (const float4*)seq,
      (const float4*)colp, (uint2*)tblG, (uint2*)tblS, (uint2*)tblC,
      P * (EDIM / 4));

  bucket_scan2_kernel<<<1, 512, 0, stream>>>(curU, baseU, NBU, curP, baseP,
                                             NBP);

  bucket_pass2_kernel<<<NBU + NBP, 256, 0, stream>>>(
      curU, baseU, regU, ptrU, csrU, U, SHU, curP, baseP, regP, ptrP, csrP, P,
      SHP, NBU);

  user_gather_kernel<<<2048, 256, 0, stream>>>(ptrU, csrU, tblG, tblS, tblC,
                                               gbf, sbf, pbf, U, NNZ);

  fusion_mfma_kernel<<<512, FM_BLK, 0, stream>>>(gbf, sbf, pbf, uemb, W, b,
                                                 hbf, U);

  poi_gather_kernel<<<2048, 256, 0, stream>>>(ptrP, csrP, hbf, init,
                                              num_layers, out, P, NNZ);
}